// Round 13
// baseline (22599.756 us; speedup 1.0000x reference)
//
#include <hip/hip_runtime.h>
#include <hip/hip_bf16.h>

#define B_ 128
#define T_ 1024
#define I_ 512
#define H_ 1024
#define O_ 512
#define NBLK 256
#define FASTTRY 64

typedef __attribute__((ext_vector_type(8))) short bf16x8;
typedef __attribute__((ext_vector_type(4))) float f32x4;
typedef __attribute__((ext_vector_type(4))) unsigned u32x4;
typedef unsigned short u16;

#define SLAB 131072  // u16 elements per 256 KB h-buffer slab

__device__ __forceinline__ unsigned f2bf_u(float f) {
  union { float f; unsigned u; } v; v.f = f;
  return (v.u + 0x7fffu + ((v.u >> 16) & 1u)) >> 16;  // RNE bf16
}

__device__ __forceinline__ bf16x8 cvt8(const float* __restrict__ p) {
  union { bf16x8 v; unsigned u[4]; } r;
  const float4 f0 = *(const float4*)p;
  const float4 f1 = *(const float4*)(p + 4);
  r.u[0] = f2bf_u(f0.x) | (f2bf_u(f0.y) << 16);
  r.u[1] = f2bf_u(f0.z) | (f2bf_u(f0.w) << 16);
  r.u[2] = f2bf_u(f1.x) | (f2bf_u(f1.y) << 16);
  r.u[3] = f2bf_u(f1.z) | (f2bf_u(f1.w) << 16);
  return r.v;
}

__device__ __forceinline__ bf16x8 cvt8r(float4 f0, float4 f1) {
  union { bf16x8 v; unsigned u[4]; } r;
  r.u[0] = f2bf_u(f0.x) | (f2bf_u(f0.y) << 16);
  r.u[1] = f2bf_u(f0.z) | (f2bf_u(f0.w) << 16);
  r.u[2] = f2bf_u(f1.x) | (f2bf_u(f1.y) << 16);
  r.u[3] = f2bf_u(f1.z) | (f2bf_u(f1.w) << 16);
  return r.v;
}

__device__ __forceinline__ bf16x8 mk8v(u32x4 t) {
  union { u32x4 u; bf16x8 b; } v;
  v.u = t & 0x7fff7fffu;
  return v.b;
}

// plain 16B load: L1/L2 cached — FAST exchange path (local-L2 served, r12)
#define LDPL(dst, base, off)                                   \
  asm volatile("global_load_dwordx4 %0, %1, off offset:" #off  \
               : "=v"(dst) : "v"(base) : "memory")
// system-scope 16B load — GUARANTEED path (r4..r12-proven; goes to HBM)
#define LDTS(dst, base, off)                                              \
  asm volatile("global_load_dwordx4 %0, %1, off offset:" #off " sc0 sc1" \
               : "=v"(dst) : "v"(base) : "memory")
// plain dword store (write-through -> local L2)
#define STPL(addr, val)                                                \
  asm volatile("global_store_dword %0, %1, off" ::"v"(addr), "v"(val)  \
               : "memory")
// system-scope dword store (shadow copy, guaranteed visibility)
#define STSC(addr, val)                                                        \
  asm volatile("global_store_dword %0, %1, off sc0 sc1" ::"v"(addr), "v"(val)  \
               : "memory")
// invalidate this CU's vector L1 (CDNA cache-maintenance op): next plain
// loads miss L1 and read fresh data from the shared local L2.
#define L1INV() asm volatile("buffer_inv" ::: "memory")

#define MFMA __builtin_amdgcn_mfma_f32_16x16x32_bf16

#define WAITV(N)                                            \
  do {                                                      \
    asm volatile("s_waitcnt vmcnt(" #N ")" ::: "memory");   \
    __builtin_amdgcn_sched_barrier(0);                      \
  } while (0)

#define ISSUE8(LD, pb)                                    \
  do {                                                    \
    const u16* _b4 = (pb) + 2048;                         \
    LD(t0, (pb), 0);    LD(t1, (pb), 1024);               \
    LD(t2, (pb), 2048); LD(t3, (pb), 3072);               \
    LD(t4, _b4, 0);     LD(t5, _b4, 1024);                \
    LD(t6, _b4, 2048);  LD(t7, _b4, 3072);                \
  } while (0)

#define TAGCHK(ok, tw)                                                  \
  do {                                                                  \
    u32x4 _m4 = (t0 ^ (tw)) | (t1 ^ (tw)) | (t2 ^ (tw)) | (t3 ^ (tw)) | \
                (t4 ^ (tw)) | (t5 ^ (tw)) | (t6 ^ (tw)) | (t7 ^ (tw));  \
    unsigned _mm = _m4.x | _m4.y | _m4.z | _m4.w;                       \
    ok = __all((_mm & 0x80008000u) == 0u);                              \
  } while (0)

// Persistent RNN. Grid = 256 blocks x 256 threads (4 waves), 1 block/CU.
// Group g = blockIdx&7 (16 batch rows) => same XCD (r12 FETCH evidence).
// Slot s = blockIdx>>3 (32 hidden cols). W tile (96 KB) in LDS.
// Exchange (r12-proven, tags = mod-3 pattern in bf16 sign bits, 8-deep
// slab rotation): fast = plain stores/loads through the shared local L2
// with buffer_inv (L1-only invalidate) between bounded retries; shadow =
// sc1 system-scope copy, store issued every step BEFORE any spin =>
// guaranteed progress under ANY block->XCD mapping.
// NEW vs r12: phase order puts __syncthreads where NO VMEM is in flight
// (its implicit vmcnt(0) drained x HBM loads + shadow-store ack every step
// = the ~2us/step invariant floor of r8..r12).
__global__ __launch_bounds__(256, 1) void rnn_persist(
    const float* __restrict__ x, const float* __restrict__ Wih,
    const float* __restrict__ bih, const float* __restrict__ Whh,
    const float* __restrict__ bhh, const float* __restrict__ Who,
    const float* __restrict__ bho, u16* __restrict__ fastb,
    u16* __restrict__ shadb, float* __restrict__ out) {
  __shared__ u16 w_lds[192 * 32 * 8];  // 96 KB
  __shared__ float red[2][256 * 9];    // 18 KB double-buffered reduce
  __shared__ float bias_lds[32];

  const int tid = threadIdx.x;
  const int w = tid >> 6;
  const int lane = tid & 63;
  const int lr = lane & 15;
  const int kg = lane >> 4;
  const int g = (int)blockIdx.x & 7;
  const int s = (int)blockIdx.x >> 3;
  const int r0 = g * 16;
  const int c0 = s * 32;

  for (int e = tid; e < 192 * 32; e += 256) {
    int o = e >> 5, c = e & 31;
    int k = o * 8, gc = c0 + c;
    const float* src = (k < H_) ? (Whh + (size_t)gc * H_ + k)
                                : (Wih + (size_t)gc * I_ + (k - H_));
    *(bf16x8*)&w_lds[e * 8] = cvt8(src);
  }
  if (tid < 32) bias_lds[tid] = bih[c0 + tid] + bhh[c0 + tid];
  __syncthreads();

  const u16* wb_h = &w_lds[(((w * 32 + kg) * 32) + lr) * 8];
  const u16* wb_x = &w_lds[(((128 + w * 16 + kg) * 32) + lr) * 8];

  const int loff = lr * 32 + kg * 8;
  const size_t twave = ((size_t)(g * 32 + w * 8)) * 512;
  const size_t towndw = ((size_t)(g * 32 + s)) * 256 + tid;

  const int rr = tid >> 4;
  const int cpair = (tid & 15) * 2;
  const int lane_r = (rr >> 2) << 4;
  const int reg_r = rr & 3;

  const f32x4 zero4 = {0.f, 0.f, 0.f, 0.f};
  f32x4 acc0, acc1;
  u32x4 t0, t1, t2, t3, t4, t5, t6, t7;
  int c3 = 0;  // t % 3

  // ---- prologue: x-part for t=0 ----
  {
    const float* px = x + ((size_t)(r0 + lr) * T_) * I_ + w * 128 + kg * 8;
    acc0 = zero4;
    acc1 = zero4;
#pragma unroll
    for (int i = 0; i < 4; ++i) {
      bf16x8 a = cvt8(px + i * 32);
      acc0 = MFMA(a, *(const bf16x8*)(wb_x + i * 1024), acc0, 0, 0, 0);
      acc1 = MFMA(a, *(const bf16x8*)(wb_x + i * 1024 + 128), acc1, 0, 0, 0);
    }
  }

#define HS(i, tv)                                                          \
  acc0 = MFMA(mk8v(tv), *(const bf16x8*)(wb_h + (i)*1024), acc0, 0, 0, 0); \
  acc1 = MFMA(mk8v(tv), *(const bf16x8*)(wb_h + (i)*1024 + 128), acc1, 0, 0, 0);

// bounded fast poll (L1INV between retries) + guaranteed shadow fallback
#define POLL_TILE(fastc, shadc, TW)                            \
  do {                                                         \
    const u16* _pb = (fastc) + twave + loff;                   \
    ISSUE8(LDPL, _pb);                                         \
    WAITV(0);                                                  \
    bool _ok;                                                  \
    TAGCHK(_ok, (TW));                                         \
    int _try = FASTTRY;                                        \
    while (!_ok && --_try >= 0) {                              \
      L1INV();                                                 \
      ISSUE8(LDPL, _pb);                                       \
      WAITV(0);                                                \
      TAGCHK(_ok, (TW));                                       \
    }                                                          \
    if (!_ok) {                                                \
      const u16* _sb = (shadc) + twave + loff;                 \
      do {                                                     \
        ISSUE8(LDTS, _sb);                                     \
        WAITV(0);                                              \
        TAGCHK(_ok, (TW));                                     \
      } while (!_ok);                                          \
    }                                                          \
  } while (0)

  for (int t = 0; t < T_; ++t) {
    const int slot = t & 7;
    const int nslot = (t + 1) & 7;
    const int c3n = (c3 == 2) ? 0 : c3 + 1;
    const unsigned tw = (c3 == 0) ? 0u : ((c3 == 1) ? 0x00008000u : 0x80000000u);
    const unsigned sp = (c3n == 0) ? 0u : ((c3n == 1) ? 0x00008000u : 0x80000000u);
    u16* fastc = fastb + (size_t)slot * SLAB;
    u16* shadc = shadb + (size_t)slot * SLAB;
    u16* fastn = fastb + (size_t)nslot * SLAB;
    u16* shadn = shadb + (size_t)nslot * SLAB;
    const bool havex = (t + 1 < T_);

    // ---- PHASE A: consume h_t (all L2-local when fast; no HBM ops live) ---
    if (t > 0) {
      POLL_TILE(fastc, shadc, tw);
      HS(0, t0) HS(1, t1) HS(2, t2) HS(3, t3)
      HS(4, t4) HS(5, t5) HS(6, t6) HS(7, t7)
    }

    // ---- PHASE C: LDS reduce; barrier has NO VMEM in flight ----
    float* redc = red[t & 1];
    *(f32x4*)&redc[(w * 64 + lane) * 9] = acc0;
    *(f32x4*)&redc[(w * 64 + lane) * 9 + 4] = acc1;
    __syncthreads();
    unsigned pkst;
    {
      const int c1 = cpair + 1;
      const int l0 = lane_r | (cpair & 15), f0 = (cpair >> 4) * 4;
      const int l1 = lane_r | (c1 & 15), f1 = (c1 >> 4) * 4;
      float v0 = 0.f, v1 = 0.f;
#pragma unroll
      for (int ww = 0; ww < 4; ++ww) {
        v0 += redc[(ww * 64 + l0) * 9 + f0 + reg_r];
        v1 += redc[(ww * 64 + l1) * 9 + f1 + reg_r];
      }
      v0 += bias_lds[cpair];
      v1 += bias_lds[c1];
      v0 = v0 > 0.f ? v0 : 0.f;
      v1 = v1 > 0.f ? v1 : 0.f;
      pkst = (f2bf_u(v0) | (f2bf_u(v1) << 16)) | sp;
      STPL((unsigned*)fastn + towndw, pkst);  // fast copy -> local L2
      STSC((unsigned*)shadn + towndw, pkst);  // shadow -> guaranteed
    }

    // ---- PHASE B: x loads for t+1 (issued AFTER the barrier) ----
    float4 xa0, xa1, xa2, xa3, xa4, xa5, xa6, xa7;
    const float* px =
        x + ((size_t)(r0 + lr) * T_ + (t + 1)) * I_ + w * 128 + kg * 8;
    if (havex) {
      xa0 = *(const float4*)(px);      xa1 = *(const float4*)(px + 4);
      xa2 = *(const float4*)(px + 32); xa3 = *(const float4*)(px + 36);
      xa4 = *(const float4*)(px + 64); xa5 = *(const float4*)(px + 68);
      xa6 = *(const float4*)(px + 96); xa7 = *(const float4*)(px + 100);
    }

    // ---- PHASE E: x MFMAs (x wait subsumes the older shadow-store ack) ----
    f32x4 xacc0 = zero4, xacc1 = zero4;
    if (havex) {
      bf16x8 a0 = cvt8r(xa0, xa1), a1 = cvt8r(xa2, xa3);
      bf16x8 a2 = cvt8r(xa4, xa5), a3 = cvt8r(xa6, xa7);
      xacc0 = MFMA(a0, *(const bf16x8*)(wb_x), xacc0, 0, 0, 0);
      xacc1 = MFMA(a0, *(const bf16x8*)(wb_x + 128), xacc1, 0, 0, 0);
      xacc0 = MFMA(a1, *(const bf16x8*)(wb_x + 1024), xacc0, 0, 0, 0);
      xacc1 = MFMA(a1, *(const bf16x8*)(wb_x + 1152), xacc1, 0, 0, 0);
      xacc0 = MFMA(a2, *(const bf16x8*)(wb_x + 2048), xacc0, 0, 0, 0);
      xacc1 = MFMA(a2, *(const bf16x8*)(wb_x + 2176), xacc1, 0, 0, 0);
      xacc0 = MFMA(a3, *(const bf16x8*)(wb_x + 3072), xacc0, 0, 0, 0);
      xacc1 = MFMA(a3, *(const bf16x8*)(wb_x + 3200), xacc1, 0, 0, 0);
    }
    acc0 = xacc0;
    acc1 = xacc1;
    c3 = c3n;
  }

  // ---- output GEMM: consume h_T (slot 0, tag pattern 1024%3 == 1) ----
  {
    const unsigned tw = 0x00008000u;
    POLL_TILE(fastb, shadb, tw);
    const int c0o = s * 16;
    f32x4 o0 = zero4;
    const float* pwo = Who + (size_t)(c0o + lr) * H_ + w * 256 + kg * 8;
    o0 = MFMA(mk8v(t0), cvt8(pwo + 0), o0, 0, 0, 0);
    o0 = MFMA(mk8v(t1), cvt8(pwo + 32), o0, 0, 0, 0);
    o0 = MFMA(mk8v(t2), cvt8(pwo + 64), o0, 0, 0, 0);
    o0 = MFMA(mk8v(t3), cvt8(pwo + 96), o0, 0, 0, 0);
    o0 = MFMA(mk8v(t4), cvt8(pwo + 128), o0, 0, 0, 0);
    o0 = MFMA(mk8v(t5), cvt8(pwo + 160), o0, 0, 0, 0);
    o0 = MFMA(mk8v(t6), cvt8(pwo + 192), o0, 0, 0, 0);
    o0 = MFMA(mk8v(t7), cvt8(pwo + 224), o0, 0, 0, 0);
    float* redc = red[0];
    *(f32x4*)&redc[(w * 64 + lane) * 9] = o0;
    __syncthreads();
    const int cc = tid & 15;
    const int l0 = lane_r | cc;
    float v = 0.f;
#pragma unroll
    for (int ww = 0; ww < 4; ++ww) v += redc[(ww * 64 + l0) * 9 + reg_r];
    v += bho[c0o + cc];
    out[(size_t)(r0 + rr) * O_ + c0o + cc] = v;
  }
}

extern "C" void kernel_launch(void* const* d_in, const int* in_sizes, int n_in,
                              void* d_out, int out_size, void* d_ws,
                              size_t ws_size, hipStream_t stream) {
  const float* x = (const float*)d_in[0];
  const float* Wih = (const float*)d_in[1];
  const float* bih = (const float*)d_in[2];
  const float* Whh = (const float*)d_in[3];
  const float* bhh = (const float*)d_in[4];
  const float* Who = (const float*)d_in[5];
  const float* bho = (const float*)d_in[6];
  float* outp = (float*)d_out;

  const size_t SB = (size_t)SLAB * 2;  // 256 KB per slab
  char* ws = (char*)d_ws;
  u16* fastb = (u16*)ws;               // 8 slabs = 2 MB (fast, L2-local)
  u16* shadb = (u16*)(ws + 8 * SB);    // 8 slabs = 2 MB (shadow, sc1)

  // slot 0 = h_0: zeros (tag pattern 0 => valid). slots 1..7: 0xFF (both
  // sign bits set => invalid under every tag pattern).
  hipMemsetAsync(ws, 0x00, SB, stream);
  hipMemsetAsync(ws + SB, 0xFF, 7 * SB, stream);
  hipMemsetAsync(ws + 8 * SB, 0x00, SB, stream);
  hipMemsetAsync(ws + 9 * SB, 0xFF, 7 * SB, stream);

  void* args[] = {(void*)&x,     (void*)&Wih,   (void*)&bih, (void*)&Whh,
                  (void*)&bhh,   (void*)&Who,   (void*)&bho, (void*)&fastb,
                  (void*)&shadb, (void*)&outp};
  hipLaunchCooperativeKernel((void*)rnn_persist, dim3(NBLK), dim3(256), args,
                             0, stream);
}

// Round 14
// 3022.551 us; speedup vs baseline: 7.4770x; 7.4770x over previous
//
#include <hip/hip_runtime.h>
#include <hip/hip_bf16.h>

#define B_ 128
#define T_ 1024
#define I_ 512
#define H_ 1024
#define O_ 512
#define NBLK 256

typedef __attribute__((ext_vector_type(8))) short bf16x8;
typedef __attribute__((ext_vector_type(4))) float f32x4;
typedef __attribute__((ext_vector_type(4))) unsigned u32x4;
typedef unsigned short u16;

#define SLAB 131072  // u16 elements per 256 KB h-buffer slab

__device__ __forceinline__ unsigned f2bf_u(float f) {
  union { float f; unsigned u; } v; v.f = f;
  return (v.u + 0x7fffu + ((v.u >> 16) & 1u)) >> 16;  // RNE bf16
}

__device__ __forceinline__ bf16x8 cvt8(const float* __restrict__ p) {
  union { bf16x8 v; unsigned u[4]; } r;
  const float4 f0 = *(const float4*)p;
  const float4 f1 = *(const float4*)(p + 4);
  r.u[0] = f2bf_u(f0.x) | (f2bf_u(f0.y) << 16);
  r.u[1] = f2bf_u(f0.z) | (f2bf_u(f0.w) << 16);
  r.u[2] = f2bf_u(f1.x) | (f2bf_u(f1.y) << 16);
  r.u[3] = f2bf_u(f1.z) | (f2bf_u(f1.w) << 16);
  return r.v;
}

__device__ __forceinline__ bf16x8 cvt8r(float4 f0, float4 f1) {
  union { bf16x8 v; unsigned u[4]; } r;
  r.u[0] = f2bf_u(f0.x) | (f2bf_u(f0.y) << 16);
  r.u[1] = f2bf_u(f0.z) | (f2bf_u(f0.w) << 16);
  r.u[2] = f2bf_u(f1.x) | (f2bf_u(f1.y) << 16);
  r.u[3] = f2bf_u(f1.z) | (f2bf_u(f1.w) << 16);
  return r.v;
}

__device__ __forceinline__ bf16x8 mk8v(u32x4 t) {
  union { u32x4 u; bf16x8 b; } v;
  v.u = t & 0x7fff7fffu;
  return v.b;
}

// plain 16B load: L1/L2 cached — FAST exchange path (local-L2 served, r12)
#define LDPL(dst, base, off)                                   \
  asm volatile("global_load_dwordx4 %0, %1, off offset:" #off  \
               : "=v"(dst) : "v"(base) : "memory")
// system-scope 16B load — GUARANTEED path (r4..r12-proven)
#define LDTS(dst, base, off)                                              \
  asm volatile("global_load_dwordx4 %0, %1, off offset:" #off " sc0 sc1" \
               : "=v"(dst) : "v"(base) : "memory")
// plain dword store (write-through -> local L2)
#define STPL(addr, val)                                                \
  asm volatile("global_store_dword %0, %1, off" ::"v"(addr), "v"(val)  \
               : "memory")
// system-scope dword store (shadow copy, guaranteed visibility)
#define STSC(addr, val)                                                        \
  asm volatile("global_store_dword %0, %1, off sc0 sc1" ::"v"(addr), "v"(val)  \
               : "memory")

#define MFMA __builtin_amdgcn_mfma_f32_16x16x32_bf16

#define WAITV(N)                                            \
  do {                                                      \
    asm volatile("s_waitcnt vmcnt(" #N ")" ::: "memory");   \
    __builtin_amdgcn_sched_barrier(0);                      \
  } while (0)

#define ISSUE8(LD, pb)                                    \
  do {                                                    \
    const u16* _b4 = (pb) + 2048;                         \
    LD(t0, (pb), 0);    LD(t1, (pb), 1024);               \
    LD(t2, (pb), 2048); LD(t3, (pb), 3072);               \
    LD(t4, _b4, 0);     LD(t5, _b4, 1024);                \
    LD(t6, _b4, 2048);  LD(t7, _b4, 3072);                \
  } while (0)

#define TAGCHK(ok, tw)                                                  \
  do {                                                                  \
    u32x4 _m4 = (t0 ^ (tw)) | (t1 ^ (tw)) | (t2 ^ (tw)) | (t3 ^ (tw)) | \
                (t4 ^ (tw)) | (t5 ^ (tw)) | (t6 ^ (tw)) | (t7 ^ (tw));  \
    unsigned _mm = _m4.x | _m4.y | _m4.z | _m4.w;                       \
    ok = __all((_mm & 0x80008000u) == 0u);                              \
  } while (0)

// single fast attempt (local L2) + guaranteed sc1 shadow fallback (r12)
#define POLL_TILE(fastc, shadc, TW)                            \
  do {                                                         \
    const u16* _pb = (fastc) + twave + loff;                   \
    ISSUE8(LDPL, _pb);                                         \
    WAITV(0);                                                  \
    bool _ok;                                                  \
    TAGCHK(_ok, (TW));                                         \
    if (!_ok) {                                                \
      const u16* _sb = (shadc) + twave + loff;                 \
      do {                                                     \
        ISSUE8(LDTS, _sb);                                     \
        WAITV(0);                                              \
        TAGCHK(_ok, (TW));                                     \
      } while (!_ok);                                          \
    }                                                          \
  } while (0)

// Persistent RNN. Grid = 256 blocks x 256 threads (4 waves), 1 block/CU.
// Group g = blockIdx&7 (16 batch rows) => same XCD (r12 FETCH evidence).
// Slot s = blockIdx>>3 (32 hidden cols). W tile (96 KB) in LDS.
// Exchange identical to r12 (PASSING): fast = plain stores/loads via shared
// local L2, single attempt; shadow = sc1 system-scope copy stored every step
// => guaranteed progress under ANY mapping; tags = mod-3 pattern in bf16
// sign bits, 8-deep slab rotation.
// NEW vs r12 (drain scheduling only):
//  - x loads issue FIRST in the step: their HBM latency drains concurrently
//    with the poll's vmcnt(0), and the barrier then has nothing in flight.
//  - shadow STSC issues AFTER the reduce (with STPL): its ~1us system ack
//    rides through phase E and drains concurrently with the NEXT poll.
__global__ __launch_bounds__(256, 1) void rnn_persist(
    const float* __restrict__ x, const float* __restrict__ Wih,
    const float* __restrict__ bih, const float* __restrict__ Whh,
    const float* __restrict__ bhh, const float* __restrict__ Who,
    const float* __restrict__ bho, u16* __restrict__ fastb,
    u16* __restrict__ shadb, float* __restrict__ out) {
  __shared__ u16 w_lds[192 * 32 * 8];  // 96 KB
  __shared__ float red[2][256 * 9];    // 18 KB double-buffered reduce
  __shared__ float bias_lds[32];

  const int tid = threadIdx.x;
  const int w = tid >> 6;
  const int lane = tid & 63;
  const int lr = lane & 15;
  const int kg = lane >> 4;
  const int g = (int)blockIdx.x & 7;
  const int s = (int)blockIdx.x >> 3;
  const int r0 = g * 16;
  const int c0 = s * 32;

  for (int e = tid; e < 192 * 32; e += 256) {
    int o = e >> 5, c = e & 31;
    int k = o * 8, gc = c0 + c;
    const float* src = (k < H_) ? (Whh + (size_t)gc * H_ + k)
                                : (Wih + (size_t)gc * I_ + (k - H_));
    *(bf16x8*)&w_lds[e * 8] = cvt8(src);
  }
  if (tid < 32) bias_lds[tid] = bih[c0 + tid] + bhh[c0 + tid];
  __syncthreads();

  const u16* wb_h = &w_lds[(((w * 32 + kg) * 32) + lr) * 8];
  const u16* wb_x = &w_lds[(((128 + w * 16 + kg) * 32) + lr) * 8];

  const int loff = lr * 32 + kg * 8;
  const size_t twave = ((size_t)(g * 32 + w * 8)) * 512;
  const size_t towndw = ((size_t)(g * 32 + s)) * 256 + tid;

  const int rr = tid >> 4;
  const int cpair = (tid & 15) * 2;
  const int lane_r = (rr >> 2) << 4;
  const int reg_r = rr & 3;

  const f32x4 zero4 = {0.f, 0.f, 0.f, 0.f};
  f32x4 acc0, acc1;
  u32x4 t0, t1, t2, t3, t4, t5, t6, t7;
  int c3 = 0;  // t % 3

  // ---- prologue: x-part for t=0 ----
  {
    const float* px = x + ((size_t)(r0 + lr) * T_) * I_ + w * 128 + kg * 8;
    acc0 = zero4;
    acc1 = zero4;
#pragma unroll
    for (int i = 0; i < 4; ++i) {
      bf16x8 a = cvt8(px + i * 32);
      acc0 = MFMA(a, *(const bf16x8*)(wb_x + i * 1024), acc0, 0, 0, 0);
      acc1 = MFMA(a, *(const bf16x8*)(wb_x + i * 1024 + 128), acc1, 0, 0, 0);
    }
  }

#define HS(i, tv)                                                          \
  acc0 = MFMA(mk8v(tv), *(const bf16x8*)(wb_h + (i)*1024), acc0, 0, 0, 0); \
  acc1 = MFMA(mk8v(tv), *(const bf16x8*)(wb_h + (i)*1024 + 128), acc1, 0, 0, 0);

  for (int t = 0; t < T_; ++t) {
    const int slot = t & 7;
    const int nslot = (t + 1) & 7;
    const int c3n = (c3 == 2) ? 0 : c3 + 1;
    const unsigned tw = (c3 == 0) ? 0u : ((c3 == 1) ? 0x00008000u : 0x80000000u);
    const unsigned sp = (c3n == 0) ? 0u : ((c3n == 1) ? 0x00008000u : 0x80000000u);
    u16* fastc = fastb + (size_t)slot * SLAB;
    u16* shadc = shadb + (size_t)slot * SLAB;
    u16* fastn = fastb + (size_t)nslot * SLAB;
    u16* shadn = shadb + (size_t)nslot * SLAB;
    const bool havex = (t + 1 < T_);

    // ---- A0: issue x loads for t+1 FIRST (drain overlaps the poll) ----
    float4 xa0, xa1, xa2, xa3, xa4, xa5, xa6, xa7;
    const float* px =
        x + ((size_t)(r0 + lr) * T_ + (t + 1)) * I_ + w * 128 + kg * 8;
    if (havex) {
      xa0 = *(const float4*)(px);      xa1 = *(const float4*)(px + 4);
      xa2 = *(const float4*)(px + 32); xa3 = *(const float4*)(px + 36);
      xa4 = *(const float4*)(px + 64); xa5 = *(const float4*)(px + 68);
      xa6 = *(const float4*)(px + 96); xa7 = *(const float4*)(px + 100);
    }

    // ---- A1: consume h_t (fast attempt + shadow fallback), h MFMAs ----
    if (t > 0) {
      POLL_TILE(fastc, shadc, tw);
      HS(0, t0) HS(1, t1) HS(2, t2) HS(3, t3)
      HS(4, t4) HS(5, t5) HS(6, t6) HS(7, t7)
    }

    // ---- C: LDS reduce (barrier: nothing in flight); pack+tag; stores ----
    float* redc = red[t & 1];
    *(f32x4*)&redc[(w * 64 + lane) * 9] = acc0;
    *(f32x4*)&redc[(w * 64 + lane) * 9 + 4] = acc1;
    __syncthreads();
    {
      const int c1 = cpair + 1;
      const int l0 = lane_r | (cpair & 15), f0 = (cpair >> 4) * 4;
      const int l1 = lane_r | (c1 & 15), f1 = (c1 >> 4) * 4;
      float v0 = 0.f, v1 = 0.f;
#pragma unroll
      for (int ww = 0; ww < 4; ++ww) {
        v0 += redc[(ww * 64 + l0) * 9 + f0 + reg_r];
        v1 += redc[(ww * 64 + l1) * 9 + f1 + reg_r];
      }
      v0 += bias_lds[cpair];
      v1 += bias_lds[c1];
      v0 = v0 > 0.f ? v0 : 0.f;
      v1 = v1 > 0.f ? v1 : 0.f;
      unsigned pkst = (f2bf_u(v0) | (f2bf_u(v1) << 16)) | sp;
      STPL((unsigned*)fastn + towndw, pkst);  // fast copy -> local L2
      STSC((unsigned*)shadn + towndw, pkst);  // shadow: ack rides to next poll
    }

    // ---- E: x MFMAs for t+1 (xa retired at the poll's vmcnt already) ----
    f32x4 xacc0 = zero4, xacc1 = zero4;
    if (havex) {
      bf16x8 a0 = cvt8r(xa0, xa1), a1 = cvt8r(xa2, xa3);
      bf16x8 a2 = cvt8r(xa4, xa5), a3 = cvt8r(xa6, xa7);
      xacc0 = MFMA(a0, *(const bf16x8*)(wb_x), xacc0, 0, 0, 0);
      xacc1 = MFMA(a0, *(const bf16x8*)(wb_x + 128), xacc1, 0, 0, 0);
      xacc0 = MFMA(a1, *(const bf16x8*)(wb_x + 1024), xacc0, 0, 0, 0);
      xacc1 = MFMA(a1, *(const bf16x8*)(wb_x + 1152), xacc1, 0, 0, 0);
      xacc0 = MFMA(a2, *(const bf16x8*)(wb_x + 2048), xacc0, 0, 0, 0);
      xacc1 = MFMA(a2, *(const bf16x8*)(wb_x + 2176), xacc1, 0, 0, 0);
      xacc0 = MFMA(a3, *(const bf16x8*)(wb_x + 3072), xacc0, 0, 0, 0);
      xacc1 = MFMA(a3, *(const bf16x8*)(wb_x + 3200), xacc1, 0, 0, 0);
    }
    acc0 = xacc0;
    acc1 = xacc1;
    c3 = c3n;
  }

  // ---- output GEMM: consume h_T (slot 0, tag pattern 1024%3 == 1) ----
  {
    const unsigned tw = 0x00008000u;
    POLL_TILE(fastb, shadb, tw);
    const int c0o = s * 16;
    f32x4 o0 = zero4;
    const float* pwo = Who + (size_t)(c0o + lr) * H_ + w * 256 + kg * 8;
    o0 = MFMA(mk8v(t0), cvt8(pwo + 0), o0, 0, 0, 0);
    o0 = MFMA(mk8v(t1), cvt8(pwo + 32), o0, 0, 0, 0);
    o0 = MFMA(mk8v(t2), cvt8(pwo + 64), o0, 0, 0, 0);
    o0 = MFMA(mk8v(t3), cvt8(pwo + 96), o0, 0, 0, 0);
    o0 = MFMA(mk8v(t4), cvt8(pwo + 128), o0, 0, 0, 0);
    o0 = MFMA(mk8v(t5), cvt8(pwo + 160), o0, 0, 0, 0);
    o0 = MFMA(mk8v(t6), cvt8(pwo + 192), o0, 0, 0, 0);
    o0 = MFMA(mk8v(t7), cvt8(pwo + 224), o0, 0, 0, 0);
    float* redc = red[0];
    *(f32x4*)&redc[(w * 64 + lane) * 9] = o0;
    __syncthreads();
    const int cc = tid & 15;
    const int l0 = lane_r | cc;
    float v = 0.f;
#pragma unroll
    for (int ww = 0; ww < 4; ++ww) v += redc[(ww * 64 + l0) * 9 + reg_r];
    v += bho[c0o + cc];
    out[(size_t)(r0 + rr) * O_ + c0o + cc] = v;
  }
}

extern "C" void kernel_launch(void* const* d_in, const int* in_sizes, int n_in,
                              void* d_out, int out_size, void* d_ws,
                              size_t ws_size, hipStream_t stream) {
  const float* x = (const float*)d_in[0];
  const float* Wih = (const float*)d_in[1];
  const float* bih = (const float*)d_in[2];
  const float* Whh = (const float*)d_in[3];
  const float* bhh = (const float*)d_in[4];
  const float* Who = (const float*)d_in[5];
  const float* bho = (const float*)d_in[6];
  float* outp = (float*)d_out;

  const size_t SB = (size_t)SLAB * 2;  // 256 KB per slab
  char* ws = (char*)d_ws;
  u16* fastb = (u16*)ws;               // 8 slabs = 2 MB (fast, L2-local)
  u16* shadb = (u16*)(ws + 8 * SB);    // 8 slabs = 2 MB (shadow, sc1)

  // slot 0 = h_0: zeros (tag pattern 0 => valid). slots 1..7: 0xFF (both
  // sign bits set => invalid under every tag pattern).
  hipMemsetAsync(ws, 0x00, SB, stream);
  hipMemsetAsync(ws + SB, 0xFF, 7 * SB, stream);
  hipMemsetAsync(ws + 8 * SB, 0x00, SB, stream);
  hipMemsetAsync(ws + 9 * SB, 0xFF, 7 * SB, stream);

  void* args[] = {(void*)&x,     (void*)&Wih,   (void*)&bih, (void*)&Whh,
                  (void*)&bhh,   (void*)&Who,   (void*)&bho, (void*)&fastb,
                  (void*)&shadb, (void*)&outp};
  hipLaunchCooperativeKernel((void*)rnn_persist, dim3(NBLK), dim3(256), args,
                             0, stream);
}

// Round 15
// 2578.214 us; speedup vs baseline: 8.7657x; 1.1723x over previous
//
#include <hip/hip_runtime.h>
#include <hip/hip_bf16.h>

#define B_ 128
#define T_ 1024
#define I_ 512
#define H_ 1024
#define O_ 512
#define NBLK 256

typedef __attribute__((ext_vector_type(8))) short bf16x8;
typedef __attribute__((ext_vector_type(4))) float f32x4;
typedef __attribute__((ext_vector_type(4))) unsigned u32x4;
typedef unsigned short u16;

#define SLAB 131072  // u16 elements per 256 KB h-buffer slab

__device__ __forceinline__ unsigned f2bf_u(float f) {
  union { float f; unsigned u; } v; v.f = f;
  return (v.u + 0x7fffu + ((v.u >> 16) & 1u)) >> 16;  // RNE bf16
}

__device__ __forceinline__ bf16x8 cvt8(const float* __restrict__ p) {
  union { bf16x8 v; unsigned u[4]; } r;
  const float4 f0 = *(const float4*)p;
  const float4 f1 = *(const float4*)(p + 4);
  r.u[0] = f2bf_u(f0.x) | (f2bf_u(f0.y) << 16);
  r.u[1] = f2bf_u(f0.z) | (f2bf_u(f0.w) << 16);
  r.u[2] = f2bf_u(f1.x) | (f2bf_u(f1.y) << 16);
  r.u[3] = f2bf_u(f1.z) | (f2bf_u(f1.w) << 16);
  return r.v;
}

// two u32x4 (raw fp32 bits) -> bf16x8
__device__ __forceinline__ bf16x8 cvt8u(u32x4 a, u32x4 b) {
  union { u32x4 u; float4 f; } ua, ub;
  ua.u = a; ub.u = b;
  union { bf16x8 v; unsigned u[4]; } r;
  r.u[0] = f2bf_u(ua.f.x) | (f2bf_u(ua.f.y) << 16);
  r.u[1] = f2bf_u(ua.f.z) | (f2bf_u(ua.f.w) << 16);
  r.u[2] = f2bf_u(ub.f.x) | (f2bf_u(ub.f.y) << 16);
  r.u[3] = f2bf_u(ub.f.z) | (f2bf_u(ub.f.w) << 16);
  return r.v;
}

__device__ __forceinline__ bf16x8 mk8v(u32x4 t) {
  union { u32x4 u; bf16x8 b; } v;
  v.u = t & 0x7fff7fffu;
  return v.b;
}

// plain 16B load (L1/L2 cached) — FAST exchange + x-stream loads
#define LDPL(dst, base, off)                                   \
  asm volatile("global_load_dwordx4 %0, %1, off offset:" #off  \
               : "=v"(dst) : "v"(base) : "memory")
// system-scope 16B load — GUARANTEED fallback (r4..r14-proven)
#define LDTS(dst, base, off)                                              \
  asm volatile("global_load_dwordx4 %0, %1, off offset:" #off " sc0 sc1" \
               : "=v"(dst) : "v"(base) : "memory")
// plain dword store (write-through -> local L2)
#define STPL(addr, val)                                                \
  asm volatile("global_store_dword %0, %1, off" ::"v"(addr), "v"(val)  \
               : "memory")
// system-scope 16B store (shadow tile; issued ONLY by wave 4)
#define STSCX4(addr, val)                                                      \
  asm volatile("global_store_dwordx4 %0, %1, off sc0 sc1" ::"v"(addr),         \
                   "v"(val)                                                    \
               : "memory")

#define MFMA __builtin_amdgcn_mfma_f32_16x16x32_bf16

// counted vmcnt wait + scheduler fence (rule #18)
#define WAITV(N)                                            \
  do {                                                      \
    asm volatile("s_waitcnt vmcnt(" #N ")" ::: "memory");   \
    __builtin_amdgcn_sched_barrier(0);                      \
  } while (0)

// raw barrier; LGKM0_BAR for producers of LDS data (m201 pattern —
// raw s_barrier does NOT drain vmcnt, so store acks ride across it)
#define LGKM0_BAR()                                           \
  do {                                                        \
    asm volatile("s_waitcnt lgkmcnt(0)" ::: "memory");        \
    __builtin_amdgcn_s_barrier();                             \
  } while (0)
#define BARO() __builtin_amdgcn_s_barrier()

#define ISSUE8(LD, pb)                                    \
  do {                                                    \
    const u16* _b4 = (pb) + 2048;                         \
    LD(t0, (pb), 0);    LD(t1, (pb), 1024);               \
    LD(t2, (pb), 2048); LD(t3, (pb), 3072);               \
    LD(t4, _b4, 0);     LD(t5, _b4, 1024);                \
    LD(t6, _b4, 2048);  LD(t7, _b4, 3072);                \
  } while (0)

#define TAGCHK(ok, tw)                                                  \
  do {                                                                  \
    u32x4 _m4 = (t0 ^ (tw)) | (t1 ^ (tw)) | (t2 ^ (tw)) | (t3 ^ (tw)) | \
                (t4 ^ (tw)) | (t5 ^ (tw)) | (t6 ^ (tw)) | (t7 ^ (tw));  \
    unsigned _mm = _m4.x | _m4.y | _m4.z | _m4.w;                       \
    ok = __all((_mm & 0x80008000u) == 0u);                              \
  } while (0)

// Persistent RNN. Grid = 256 blocks x 320 threads (4 compute waves + 1
// shadow-store wave). Group g = blockIdx&7 (16 batch rows, same XCD —
// r12/r14 FETCH evidence); slot s = blockIdx>>3 (32 hidden cols).
// Exchange protocol identical to r12/r14 (PASSING): fast = plain
// store/load via shared local L2, single attempt, mod-3 tag in bf16 sign
// bits, 8-deep slab rotation; shadow = sc1 system-scope copy (guaranteed
// under ANY mapping). NEW (waitcnt schedule ownership):
//  - polls issued FIRST, x loads behind them; vmcnt(8) checks polls while
//    x HBM latency stays off the h-critical path (in-order retirement).
//  - raw s_barrier + hand lgkmcnt: no vmcnt(0) at barriers; STPL acks
//    ride into the next step's vmcnt(8) (free).
//  - wave 4 owns ALL system-scope stores: compute waves' VMEM queues
//    never contain a ~1us system ack.
__global__ __launch_bounds__(320, 1) void rnn_persist(
    const float* __restrict__ x, const float* __restrict__ Wih,
    const float* __restrict__ bih, const float* __restrict__ Whh,
    const float* __restrict__ bhh, const float* __restrict__ Who,
    const float* __restrict__ bho, u16* __restrict__ fastb,
    u16* __restrict__ shadb, float* __restrict__ out) {
  __shared__ u16 w_lds[192 * 32 * 8];   // 96 KB
  __shared__ float red[2][256 * 9];     // 18 KB double-buffered reduce
  __shared__ unsigned pk_lds[2][256];   // 2 KB packed-tile for wave 4
  __shared__ float bias_lds[32];

  const int tid = threadIdx.x;
  const int w = tid >> 6;           // 0..4
  const int lane = tid & 63;
  const int lr = lane & 15;
  const int kg = lane >> 4;
  const int g = (int)blockIdx.x & 7;
  const int s = (int)blockIdx.x >> 3;
  const int r0 = g * 16;
  const int c0 = s * 32;
  const size_t tilebase = ((size_t)(g * 32 + s)) * 256;

  // ---- stage W tile [32 cols x 1536 K] into LDS (all 320 threads) ----
  for (int e = tid; e < 192 * 32; e += 320) {
    int o = e >> 5, c = e & 31;
    int k = o * 8, gc = c0 + c;
    const float* src = (k < H_) ? (Whh + (size_t)gc * H_ + k)
                                : (Wih + (size_t)gc * I_ + (k - H_));
    *(bf16x8*)&w_lds[e * 8] = cvt8(src);
  }
  if (tid < 32) bias_lds[tid] = bih[c0 + tid] + bhh[c0 + tid];
  __syncthreads();

  // ================= wave 4: shadow-store service =================
  if (w == 4) {
    for (int t = 0; t < T_; ++t) {
      BARO();  // B1
      BARO();  // B2 -> pk_lds[t&1] complete
      const int nslot = (t + 1) & 7;
      u32x4 pv = *(const u32x4*)&pk_lds[t & 1][lane * 4];
      unsigned* sdst =
          (unsigned*)(shadb + (size_t)nslot * SLAB) + tilebase + lane * 4;
      STSCX4(sdst, pv);  // ack never drained by anyone
    }
    BARO();  // epilogue barrier
    return;
  }

  // ================= compute waves (w = 0..3) =================
  const u16* wb_h = &w_lds[(((w * 32 + kg) * 32) + lr) * 8];
  const u16* wb_x = &w_lds[(((128 + w * 16 + kg) * 32) + lr) * 8];
  const int loff = lr * 32 + kg * 8;
  const size_t twave = ((size_t)(g * 32 + w * 8)) * 512;
  const size_t towndw = tilebase + tid;

  const int rr = tid >> 4;
  const int cpair = (tid & 15) * 2;
  const int lane_r = (rr >> 2) << 4;
  const int reg_r = rr & 3;

  const f32x4 zero4 = {0.f, 0.f, 0.f, 0.f};
  f32x4 acc0, acc1;
  u32x4 t0, t1, t2, t3, t4, t5, t6, t7;
  u32x4 xa0, xa1, xa2, xa3, xa4, xa5, xa6, xa7;
  int c3 = 0;  // t % 3

  // ---- prologue: x-part for t=0 (C-level loads, pre-loop) ----
  {
    const float* px = x + ((size_t)(r0 + lr) * T_) * I_ + w * 128 + kg * 8;
    acc0 = zero4;
    acc1 = zero4;
#pragma unroll
    for (int i = 0; i < 4; ++i) {
      bf16x8 a = cvt8(px + i * 32);
      acc0 = MFMA(a, *(const bf16x8*)(wb_x + i * 1024), acc0, 0, 0, 0);
      acc1 = MFMA(a, *(const bf16x8*)(wb_x + i * 1024 + 128), acc1, 0, 0, 0);
    }
  }

#define HS(i, tv)                                                          \
  acc0 = MFMA(mk8v(tv), *(const bf16x8*)(wb_h + (i)*1024), acc0, 0, 0, 0); \
  acc1 = MFMA(mk8v(tv), *(const bf16x8*)(wb_h + (i)*1024 + 128), acc1, 0, 0, 0);

  for (int t = 0; t < T_; ++t) {
    const int slot = t & 7;
    const int nslot = (t + 1) & 7;
    const int c3n = (c3 == 2) ? 0 : c3 + 1;
    const unsigned tw = (c3 == 0) ? 0u : ((c3 == 1) ? 0x00008000u : 0x80000000u);
    const unsigned sp = (c3n == 0) ? 0u : ((c3n == 1) ? 0x00008000u : 0x80000000u);
    u16* fastc = fastb + (size_t)slot * SLAB;
    u16* shadc = shadb + (size_t)slot * SLAB;
    u16* fastn = fastb + (size_t)nslot * SLAB;
    const bool havex = (t + 1 < T_);

    // ---- A: polls FIRST, x loads behind them ----
    if (t > 0) {
      const u16* pb = fastc + twave + loff;
      ISSUE8(LDPL, pb);
    }
    if (havex) {
      const u16* pxb =
          (const u16*)(x + ((size_t)(r0 + lr) * T_ + (t + 1)) * I_ + w * 128 +
                       kg * 8);
      LDPL(xa0, pxb, 0);   LDPL(xa1, pxb, 16);
      LDPL(xa2, pxb, 128); LDPL(xa3, pxb, 144);
      LDPL(xa4, pxb, 256); LDPL(xa5, pxb, 272);
      LDPL(xa6, pxb, 384); LDPL(xa7, pxb, 400);
    }

    if (t > 0) {
      // queue: [STPL_prev, polls x8, (xa x8)] — vmcnt(8) retires the
      // prev STPL ack (free) + all polls, leaves xa in flight.
      if (havex) { WAITV(8); } else { WAITV(0); }
      bool ok;
      TAGCHK(ok, tw);
      if (!ok) {  // guaranteed path (rare): sc1 loop on shadow copy
        const u16* sb = shadc + twave + loff;
        do {
          ISSUE8(LDTS, sb);
          WAITV(0);
          TAGCHK(ok, tw);
        } while (!ok);
      }
      HS(0, t0) HS(1, t1) HS(2, t2) HS(3, t3)
      HS(4, t4) HS(5, t5) HS(6, t6) HS(7, t7)
    }

    // ---- C: K-reduce across waves (raw barriers, no vmcnt drain) ----
    float* redc = red[t & 1];
    *(f32x4*)&redc[(w * 64 + lane) * 9] = acc0;
    *(f32x4*)&redc[(w * 64 + lane) * 9 + 4] = acc1;
    LGKM0_BAR();  // B1
    {
      const int c1 = cpair + 1;
      const int l0 = lane_r | (cpair & 15), f0 = (cpair >> 4) * 4;
      const int l1 = lane_r | (c1 & 15), f1 = (c1 >> 4) * 4;
      float v0 = 0.f, v1 = 0.f;
#pragma unroll
      for (int ww = 0; ww < 4; ++ww) {
        v0 += redc[(ww * 64 + l0) * 9 + f0 + reg_r];
        v1 += redc[(ww * 64 + l1) * 9 + f1 + reg_r];
      }
      v0 += bias_lds[cpair];
      v1 += bias_lds[c1];
      v0 = v0 > 0.f ? v0 : 0.f;
      v1 = v1 > 0.f ? v1 : 0.f;
      unsigned pkst = (f2bf_u(v0) | (f2bf_u(v1) << 16)) | sp;
      STPL((unsigned*)fastn + towndw, pkst);  // fast copy -> local L2
      pk_lds[t & 1][tid] = pkst;              // hand tile to wave 4
    }
    LGKM0_BAR();  // B2

    // ---- E: x MFMAs; vmcnt(1) leaves the STPL ack in flight ----
    f32x4 xacc0 = zero4, xacc1 = zero4;
    if (havex) {
      WAITV(1);
      bf16x8 a0 = cvt8u(xa0, xa1), a1 = cvt8u(xa2, xa3);
      bf16x8 a2 = cvt8u(xa4, xa5), a3 = cvt8u(xa6, xa7);
      xacc0 = MFMA(a0, *(const bf16x8*)(wb_x), xacc0, 0, 0, 0);
      xacc1 = MFMA(a0, *(const bf16x8*)(wb_x + 128), xacc1, 0, 0, 0);
      xacc0 = MFMA(a1, *(const bf16x8*)(wb_x + 1024), xacc0, 0, 0, 0);
      xacc1 = MFMA(a1, *(const bf16x8*)(wb_x + 1152), xacc1, 0, 0, 0);
      xacc0 = MFMA(a2, *(const bf16x8*)(wb_x + 2048), xacc0, 0, 0, 0);
      xacc1 = MFMA(a2, *(const bf16x8*)(wb_x + 2176), xacc1, 0, 0, 0);
      xacc0 = MFMA(a3, *(const bf16x8*)(wb_x + 3072), xacc0, 0, 0, 0);
      xacc1 = MFMA(a3, *(const bf16x8*)(wb_x + 3200), xacc1, 0, 0, 0);
    }
    acc0 = xacc0;
    acc1 = xacc1;
    c3 = c3n;
  }

  // ---- output GEMM: consume h_T (slot 0, tag pattern 1024%3 == 1) ----
  {
    const unsigned tw = 0x00008000u;
    const u16* pb = fastb + twave + loff;
    ISSUE8(LDPL, pb);
    WAITV(0);
    bool ok;
    TAGCHK(ok, tw);
    if (!ok) {
      const u16* sb = shadb + twave + loff;
      do {
        ISSUE8(LDTS, sb);
        WAITV(0);
        TAGCHK(ok, tw);
      } while (!ok);
    }
    const int c0o = s * 16;
    f32x4 o0 = zero4;
    const float* pwo = Who + (size_t)(c0o + lr) * H_ + w * 256 + kg * 8;
    o0 = MFMA(mk8v(t0), cvt8(pwo + 0), o0, 0, 0, 0);
    o0 = MFMA(mk8v(t1), cvt8(pwo + 32), o0, 0, 0, 0);
    o0 = MFMA(mk8v(t2), cvt8(pwo + 64), o0, 0, 0, 0);
    o0 = MFMA(mk8v(t3), cvt8(pwo + 96), o0, 0, 0, 0);
    o0 = MFMA(mk8v(t4), cvt8(pwo + 128), o0, 0, 0, 0);
    o0 = MFMA(mk8v(t5), cvt8(pwo + 160), o0, 0, 0, 0);
    o0 = MFMA(mk8v(t6), cvt8(pwo + 192), o0, 0, 0, 0);
    o0 = MFMA(mk8v(t7), cvt8(pwo + 224), o0, 0, 0, 0);
    float* redc = red[0];
    *(f32x4*)&redc[(w * 64 + lane) * 9] = o0;
    LGKM0_BAR();  // epilogue barrier (matches wave 4's final BARO)
    const int cc = tid & 15;
    const int l0 = lane_r | cc;
    float v = 0.f;
#pragma unroll
    for (int ww = 0; ww < 4; ++ww) v += redc[(ww * 64 + l0) * 9 + reg_r];
    v += bho[c0o + cc];
    out[(size_t)(r0 + rr) * O_ + c0o + cc] = v;
  }
}

extern "C" void kernel_launch(void* const* d_in, const int* in_sizes, int n_in,
                              void* d_out, int out_size, void* d_ws,
                              size_t ws_size, hipStream_t stream) {
  const float* x = (const float*)d_in[0];
  const float* Wih = (const float*)d_in[1];
  const float* bih = (const float*)d_in[2];
  const float* Whh = (const float*)d_in[3];
  const float* bhh = (const float*)d_in[4];
  const float* Who = (const float*)d_in[5];
  const float* bho = (const float*)d_in[6];
  float* outp = (float*)d_out;

  const size_t SB = (size_t)SLAB * 2;  // 256 KB per slab
  char* ws = (char*)d_ws;
  u16* fastb = (u16*)ws;               // 8 slabs = 2 MB (fast, L2-local)
  u16* shadb = (u16*)(ws + 8 * SB);    // 8 slabs = 2 MB (shadow, sc1)

  // slot 0 = h_0: zeros (tag pattern 0 => valid). slots 1..7: 0xFF (both
  // sign bits set => invalid under every tag pattern).
  hipMemsetAsync(ws, 0x00, SB, stream);
  hipMemsetAsync(ws + SB, 0xFF, 7 * SB, stream);
  hipMemsetAsync(ws + 8 * SB, 0x00, SB, stream);
  hipMemsetAsync(ws + 9 * SB, 0xFF, 7 * SB, stream);

  void* args[] = {(void*)&x,     (void*)&Wih,   (void*)&bih, (void*)&Whh,
                  (void*)&bhh,   (void*)&Who,   (void*)&bho, (void*)&fastb,
                  (void*)&shadb, (void*)&outp};
  hipLaunchCooperativeKernel((void*)rnn_persist, dim3(NBLK), dim3(320), args,
                             0, stream);
}